// Round 3
// baseline (1624.531 us; speedup 1.0000x reference)
//
#include <hip/hip_runtime.h>
#include <math.h>

// Problem constants
#define BC 32
#define HHH 56
#define WWW 56
#define CCH 384
#define NHEADS 12
#define PH 28
#define PW 28
#define NP (PH*PW)          // 784
#define NA 972              // 9*9*12
#define APAD 1024           // padded row stride for attention logits
#define KC 1152             // concatenated K' = 3*384 (A: hi|hi|lo vs B: hi|lo|hi)
#define SCALE 0.17677669529663688f  // 1/sqrt(32)

typedef short bf16x8 __attribute__((ext_vector_type(8)));
typedef float f32x4 __attribute__((ext_vector_type(4)));

__device__ __forceinline__ ushort bf16_trunc(float x) {
    return (ushort)(__float_as_uint(x) >> 16);
}
__device__ __forceinline__ float bf16_to_f32(ushort h) {
    return __uint_as_float(((unsigned int)h) << 16);
}

// ---------------------------------------------------------------------------
// Weight conversion: W[384][N] fp32 -> BT[Npad][1152] bf16 (n-major).
// BT[n][k]=hi(W[k][n]); BT[n][384+k]=lo(W[k][n]); BT[n][768+k]=hi(W[k][n]).
// Pairs with A-cat [Ahi | Ahi | Alo] -> Ahi*Bhi + Ahi*Blo + Alo*Bhi.
// ---------------------------------------------------------------------------
__global__ __launch_bounds__(256)
void convw_kernel(const float* __restrict__ W, ushort* __restrict__ BT,
                  int N, int Npad) {
    const int n = blockIdx.x * 4 + (threadIdx.x >> 6);
    const int lane = threadIdx.x & 63;
    if (n >= Npad) return;
    ushort* row = BT + (size_t)n * KC;
    #pragma unroll
    for (int t = 0; t < 6; ++t) {
        int k = t * 64 + lane;
        float wv = (n < N) ? W[(size_t)k * N + n] : 0.0f;
        ushort hi = bf16_trunc(wv);
        ushort lo = bf16_trunc(wv - bf16_to_f32(hi));
        row[k] = hi;
        row[384 + k] = lo;
        row[768 + k] = hi;
    }
}

// ---------------------------------------------------------------------------
// Split-bf16 MFMA GEMM: C[M][Cstride] = A_f32[M][384] (x) BT[Npad][1152] (+bias)
// Tile 128x128, BK=64 (cat-k), 4 waves 2x2, 4x4 16x16x32_bf16 frags per wave.
// A is converted fp32->bf16 (hi or lo per K-region) during staging.
// LDS tiles [row][64] bf16 with 16B-unit XOR swizzle (unit ^= row&7), applied
// identically on write and read (both-sides rule).
// ---------------------------------------------------------------------------
template<bool BIAS>
__global__ __launch_bounds__(256)
void mfma_gemm(const float* __restrict__ A, const ushort* __restrict__ BT,
               const float* __restrict__ bias, float* __restrict__ C,
               int Cstride, int Nbias) {
    __shared__ ushort As[128 * 64];
    __shared__ ushort Bs[128 * 64];
    const int n0 = blockIdx.x * 128;
    const int m0 = blockIdx.y * 128;
    const int tid = threadIdx.x;
    const int lane = tid & 63;
    const int wave = tid >> 6;
    const int mw0 = (wave >> 1) * 64;
    const int nw0 = (wave & 1) * 64;

    f32x4 acc[4][4];
    #pragma unroll
    for (int i = 0; i < 4; ++i)
        #pragma unroll
        for (int j = 0; j < 4; ++j)
            #pragma unroll
            for (int r = 0; r < 4; ++r)
                acc[i][j][r] = 0.0f;

    char* AsB = reinterpret_cast<char*>(As);
    char* BsB = reinterpret_cast<char*>(Bs);

    for (int s = 0; s < 18; ++s) {
        const int k0 = (s % 6) * 64;       // original fp32 column block
        const bool lo_mode = (s >= 12);    // steps 0-11: hi, 12-17: lo

        // ---- stage A: 128 rows x 64 fp32 -> bf16, 8 float4 per thread ----
        #pragma unroll
        for (int l = 0; l < 8; ++l) {
            int fid = tid + l * 256;       // 0..2047
            int r = fid >> 4;              // row 0..127
            int c4 = fid & 15;             // float4 granule (16 per row)
            float4 av = *reinterpret_cast<const float4*>(
                &A[(size_t)(m0 + r) * CCH + k0 + c4 * 4]);
            float vals[4] = {av.x, av.y, av.z, av.w};
            ushort4 hv;
            ushort tmp[4];
            #pragma unroll
            for (int q = 0; q < 4; ++q) {
                ushort hi = bf16_trunc(vals[q]);
                tmp[q] = lo_mode ? bf16_trunc(vals[q] - bf16_to_f32(hi)) : hi;
            }
            hv.x = tmp[0]; hv.y = tmp[1]; hv.z = tmp[2]; hv.w = tmp[3];
            int byteoff = r * 128 + ((((c4 >> 1) ^ (r & 7)) << 4)) + (c4 & 1) * 8;
            *reinterpret_cast<ushort4*>(AsB + byteoff) = hv;
        }
        // ---- stage B: 128 rows x 64 bf16 linear copy, 4 int4 per thread ----
        #pragma unroll
        for (int l = 0; l < 4; ++l) {
            int fid = tid + l * 256;       // 0..1023
            int r = fid >> 3;              // n-row 0..127
            int u = fid & 7;               // 16B unit
            int4 bv = *reinterpret_cast<const int4*>(
                &BT[(size_t)(n0 + r) * KC + s * 64 + u * 8]);
            int byteoff = r * 128 + ((u ^ (r & 7)) << 4);
            *reinterpret_cast<int4*>(BsB + byteoff) = bv;
        }
        __syncthreads();

        #pragma unroll
        for (int kf = 0; kf < 2; ++kf) {
            bf16x8 af[4], bfr[4];
            #pragma unroll
            for (int fm = 0; fm < 4; ++fm) {
                int row = mw0 + fm * 16 + (lane & 15);
                int unit = kf * 4 + (lane >> 4);
                af[fm] = *reinterpret_cast<bf16x8*>(
                    AsB + row * 128 + ((unit ^ (row & 7)) << 4));
            }
            #pragma unroll
            for (int fn = 0; fn < 4; ++fn) {
                int row = nw0 + fn * 16 + (lane & 15);
                int unit = kf * 4 + (lane >> 4);
                bfr[fn] = *reinterpret_cast<bf16x8*>(
                    BsB + row * 128 + ((unit ^ (row & 7)) << 4));
            }
            #pragma unroll
            for (int fm = 0; fm < 4; ++fm)
                #pragma unroll
                for (int fn = 0; fn < 4; ++fn)
                    acc[fm][fn] = __builtin_amdgcn_mfma_f32_16x16x32_bf16(
                        af[fm], bfr[fn], acc[fm][fn], 0, 0, 0);
        }
        __syncthreads();
    }

    // ---- epilogue: C/D layout col=lane&15, row=(lane>>4)*4+reg (m89) ----
    #pragma unroll
    for (int fm = 0; fm < 4; ++fm) {
        #pragma unroll
        for (int fn = 0; fn < 4; ++fn) {
            int col = n0 + nw0 + fn * 16 + (lane & 15);
            float bv = 0.0f;
            if (BIAS) bv = (col < Nbias) ? bias[col] : 0.0f;
            #pragma unroll
            for (int r = 0; r < 4; ++r) {
                int row = m0 + mw0 + fm * 16 + (lane >> 4) * 4 + r;
                C[(size_t)row * Cstride + col] = acc[fm][fn][r] + bv;
            }
        }
    }
}

// ---------------------------------------------------------------------------
// 2x2 mean pool: x[B,56,56,C] -> xp[B,28,28,C], float4-vectorized (G13).
// ---------------------------------------------------------------------------
__global__ void pool_kernel(const float* __restrict__ x, float* __restrict__ xp) {
    int idx = blockIdx.x * blockDim.x + threadIdx.x;
    const int total = BC * PH * PW * (CCH / 4);
    if (idx >= total) return;
    int c4 = idx % (CCH / 4); int t = idx / (CCH / 4);
    int pw = t % PW; t /= PW; int ph = t % PH; int b = t / PH;
    const float* base = x + (((size_t)b * HHH + ph * 2) * WWW + pw * 2) * CCH + c4 * 4;
    const size_t rs = (size_t)WWW * CCH;
    float4 v0 = *reinterpret_cast<const float4*>(base);
    float4 v1 = *reinterpret_cast<const float4*>(base + CCH);
    float4 v2 = *reinterpret_cast<const float4*>(base + rs);
    float4 v3 = *reinterpret_cast<const float4*>(base + rs + CCH);
    float4 o;
    o.x = 0.25f * (v0.x + v1.x + v2.x + v3.x);
    o.y = 0.25f * (v0.y + v1.y + v2.y + v3.y);
    o.z = 0.25f * (v0.z + v1.z + v2.z + v3.z);
    o.w = 0.25f * (v0.w + v1.w + v2.w + v3.w);
    *reinterpret_cast<float4*>(
        xp + (((size_t)(b * PH + ph) * PW + pw) * CCH) + c4 * 4) = o;
}

// ---------------------------------------------------------------------------
// Softmax over k (9 contiguous elems), rows of stride APAD, 108 groups/row.
// ---------------------------------------------------------------------------
__global__ void softmax_kernel(float* __restrict__ a) {
    int idx = blockIdx.x * blockDim.x + threadIdx.x;
    const int total = BC * NP * 108;
    if (idx >= total) return;
    int row = idx / 108;
    int rem = idx % 108;
    float* p = a + (size_t)row * APAD + rem * 9;
    float vbuf[9];
    float m = -1e30f;
    #pragma unroll
    for (int k = 0; k < 9; ++k) { vbuf[k] = p[k] * SCALE; m = fmaxf(m, vbuf[k]); }
    float s = 0.f;
    #pragma unroll
    for (int k = 0; k < 9; ++k) { vbuf[k] = __expf(vbuf[k] - m); s += vbuf[k]; }
    float inv = 1.0f / s;
    #pragma unroll
    for (int k = 0; k < 9; ++k) p[k] = vbuf[k] * inv;
}

// ---------------------------------------------------------------------------
// Gather-fold: out[pix][c] = sum over contributing (patch,q) pairs and 3x3 k
// window of a[p,n,q,k] * v[neighbor pixel][c].  Block = pixel, thread = chan.
// ---------------------------------------------------------------------------
__global__ __launch_bounds__(384)
void gather_kernel(const float* __restrict__ v, const float* __restrict__ a,
                   float* __restrict__ y) {
    const int pix = blockIdx.x;          // b*56*56 + i*56 + j
    const int c = threadIdx.x;
    const int j = pix % WWW;
    const int t = pix / WWW;
    const int i = t % HHH;
    const int b = t / HHH;
    const int n = c >> 5;                // head

    int phs[2], qas[2]; int nr = 0;
    if ((i & 1) == 0) { phs[0] = i >> 1; qas[0] = 1; nr = 1; }
    else {
        if (((i + 1) >> 1) < PH) { phs[nr] = (i + 1) >> 1; qas[nr] = 0; ++nr; }
        phs[nr] = (i - 1) >> 1; qas[nr] = 2; ++nr;
    }
    int pws[2], qbs[2]; int nc = 0;
    if ((j & 1) == 0) { pws[0] = j >> 1; qbs[0] = 1; nc = 1; }
    else {
        if (((j + 1) >> 1) < PW) { pws[nc] = (j + 1) >> 1; qbs[nc] = 0; ++nc; }
        pws[nc] = (j - 1) >> 1; qbs[nc] = 2; ++nc;
    }

    float acc = 0.f;
    for (int ri = 0; ri < nr; ++ri) {
        for (int ci = 0; ci < nc; ++ci) {
            const int ph = phs[ri], pw = pws[ci];
            const int q = qas[ri] * 3 + qbs[ci];
            const int p = ph * PW + pw;
            const float* ap = a + (size_t)(b * NP + p) * APAD + n * 81 + q * 9;
            const int vi0 = ph * 2 - 1, vj0 = pw * 2 - 1;
            #pragma unroll
            for (int ki = 0; ki < 3; ++ki) {
                const int vi = vi0 + ki;
                if (vi < 0 || vi >= HHH) continue;
                #pragma unroll
                for (int kj = 0; kj < 3; ++kj) {
                    const int vj = vj0 + kj;
                    if (vj < 0 || vj >= WWW) continue;
                    acc += ap[ki * 3 + kj] *
                           v[(((size_t)b * HHH + vi) * WWW + vj) * CCH + c];
                }
            }
        }
    }
    y[(size_t)pix * CCH + c] = acc;
}

// ---------------------------------------------------------------------------
extern "C" void kernel_launch(void* const* d_in, const int* in_sizes, int n_in,
                              void* d_out, int out_size, void* d_ws, size_t ws_size,
                              hipStream_t stream) {
    const float* x   = (const float*)d_in[0];
    const float* W_v = (const float*)d_in[1];
    const float* W_a = (const float*)d_in[2];
    const float* b_a = (const float*)d_in[3];
    const float* W_o = (const float*)d_in[4];
    const float* b_o = (const float*)d_in[5];
    float* out = (float*)d_out;
    float* ws  = (float*)d_ws;

    // Workspace layout (floats):
    //   Y (ypre, also hosts xp early): 38,535,168   (154.1 MB)
    //   a (stride 1024):               25,690,112   (102.8 MB)
    //   WvT/WaT/WoT bf16:               2,064,384 ushorts (4.1 MB)
    // Total ~261 MB.  v lives in d_out between GEMM1 and GEMM3.
    float*  Y   = ws;
    float*  a   = ws + 38535168;
    ushort* WvT = (ushort*)(ws + 38535168 + 25690112);
    ushort* WaT = WvT + (size_t)384 * KC;
    ushort* WoT = WaT + (size_t)1024 * KC;
    float*  xp  = Y;                 // pool scratch; dead before gather writes Y
    float*  v   = out;               // v lives in d_out until GEMM3 overwrites

    const int M1 = BC * HHH * WWW;   // 100352

    // 0) weight conversions (hi|lo|hi transposed cat layout)
    convw_kernel<<<96,  256, 0, stream>>>(W_v, WvT, 384, 384);
    convw_kernel<<<256, 256, 0, stream>>>(W_a, WaT, NA,  1024);
    convw_kernel<<<96,  256, 0, stream>>>(W_o, WoT, 384, 384);
    // 1) pool into Y-region scratch
    pool_kernel<<<(BC*PH*PW*(CCH/4) + 255) / 256, 256, 0, stream>>>(x, xp);
    // 2) a = xp @ W_a + b_a   (25088 x 1024, K'=1152)
    mfma_gemm<true><<<dim3(8, 196), 256, 0, stream>>>(xp, WaT, b_a, a, APAD, NA);
    // 3) softmax over k
    softmax_kernel<<<(BC*NP*108 + 255) / 256, 256, 0, stream>>>(a);
    // 4) v = x @ W_v -> d_out (100352 x 384)
    mfma_gemm<false><<<dim3(3, 784), 256, 0, stream>>>(x, WvT, nullptr, v, CCH, CCH);
    // 5) gather-fold: reads v (d_out) + a -> writes ypre into Y (ws)
    gather_kernel<<<M1, 384, 0, stream>>>(v, a, Y);
    // 6) y = ypre @ W_o + b_o: reads Y (ws) -> writes d_out. No alias, no copy.
    mfma_gemm<true><<<dim3(3, 784), 256, 0, stream>>>(Y, WoT, b_o, out, CCH, CCH);
}

// Round 5
// 982.403 us; speedup vs baseline: 1.6536x; 1.6536x over previous
//
#include <hip/hip_runtime.h>
#include <math.h>

// Problem constants
#define BC 32
#define HHH 56
#define WWW 56
#define CCH 384
#define NHEADS 12
#define PH 28
#define PW 28
#define NP (PH*PW)          // 784
#define NA 972              // 9*9*12
#define APAD 1024           // padded row stride for attention logits
#define KC 1152             // BT row stride: [hi(384) | lo(384) | unused(384)]
#define SCALE 0.17677669529663688f  // 1/sqrt(32)

typedef short bf16x8 __attribute__((ext_vector_type(8)));
typedef float f32x4 __attribute__((ext_vector_type(4)));

__device__ __forceinline__ ushort bf16_trunc(float x) {
    return (ushort)(__float_as_uint(x) >> 16);
}
__device__ __forceinline__ float bf16_to_f32(ushort h) {
    return __uint_as_float(((unsigned int)h) << 16);
}

// ---------------------------------------------------------------------------
// Weight conversion: W[384][N] fp32 -> BT[Npad][1152] bf16 (n-major).
// BT[n][k]=hi(W[k][n]); BT[n][384+k]=lo(W[k][n]); region 2 legacy (unused).
// ---------------------------------------------------------------------------
__global__ __launch_bounds__(256)
void convw_kernel(const float* __restrict__ W, ushort* __restrict__ BT,
                  int N, int Npad) {
    const int n = blockIdx.x * 4 + (threadIdx.x >> 6);
    const int lane = threadIdx.x & 63;
    if (n >= Npad) return;
    ushort* row = BT + (size_t)n * KC;
    #pragma unroll
    for (int t = 0; t < 6; ++t) {
        int k = t * 64 + lane;
        float wv = (n < N) ? W[(size_t)k * N + n] : 0.0f;
        ushort hi = bf16_trunc(wv);
        ushort lo = bf16_trunc(wv - bf16_to_f32(hi));
        row[k] = hi;
        row[384 + k] = lo;
        row[768 + k] = hi;
    }
}

// ---------------------------------------------------------------------------
// Split-bf16 MFMA GEMM, "A-once" schedule:
//   C = Ahi*Bhi + Alo*Bhi + Ahi*Blo  (fp32-grade via 3-term bf16 split)
// Tile 128x128, 6 k-blocks of 64; per k-block:
//   stage A fp32 once -> {Ah, Al} LDS tiles; phase1 B=Bhi: Ah*B + Al*B;
//   phase2 B=Blo: Ah*B.  4 waves 2x2, 4x4 16x16x32_bf16 frags per wave.
// LDS 48 KB (3 tiles) -> 3 blocks/CU.  16B-unit XOR swizzle (unit ^= row&7)
// on both write and read.
// ---------------------------------------------------------------------------
template<bool BIAS>
__global__ __launch_bounds__(256)
void mfma_gemm(const float* __restrict__ A, const ushort* __restrict__ BT,
               const float* __restrict__ bias, float* __restrict__ C,
               int Cstride, int Nbias) {
    __shared__ ushort Ah[128 * 64];
    __shared__ ushort Al[128 * 64];
    __shared__ ushort Bs[128 * 64];
    const int n0 = blockIdx.x * 128;
    const int m0 = blockIdx.y * 128;
    const int tid = threadIdx.x;
    const int lane = tid & 63;
    const int wave = tid >> 6;
    const int mw0 = (wave >> 1) * 64;
    const int nw0 = (wave & 1) * 64;

    f32x4 acc[4][4];
    #pragma unroll
    for (int i = 0; i < 4; ++i)
        #pragma unroll
        for (int j = 0; j < 4; ++j)
            #pragma unroll
            for (int r = 0; r < 4; ++r)
                acc[i][j][r] = 0.0f;

    char* AhB = reinterpret_cast<char*>(Ah);
    char* AlB = reinterpret_cast<char*>(Al);
    char* BsB = reinterpret_cast<char*>(Bs);

    for (int k0b = 0; k0b < 6; ++k0b) {
        const int k0 = k0b * 64;

        // ---- stage A once: 128 rows x 64 fp32 -> (hi, lo), 8 float4/thread --
        #pragma unroll
        for (int l = 0; l < 8; ++l) {
            int fid = tid + l * 256;       // 0..2047
            int r = fid >> 4;              // row 0..127
            int c4 = fid & 15;             // float4 granule (16 per row)
            float4 av = *reinterpret_cast<const float4*>(
                &A[(size_t)(m0 + r) * CCH + k0 + c4 * 4]);
            float vals[4] = {av.x, av.y, av.z, av.w};
            ushort4 hv, lv;
            ushort th[4], tl[4];
            #pragma unroll
            for (int q = 0; q < 4; ++q) {
                th[q] = bf16_trunc(vals[q]);
                tl[q] = bf16_trunc(vals[q] - bf16_to_f32(th[q]));
            }
            hv.x = th[0]; hv.y = th[1]; hv.z = th[2]; hv.w = th[3];
            lv.x = tl[0]; lv.y = tl[1]; lv.z = tl[2]; lv.w = tl[3];
            int byteoff = r * 128 + ((((c4 >> 1) ^ (r & 7)) << 4)) + (c4 & 1) * 8;
            *reinterpret_cast<ushort4*>(AhB + byteoff) = hv;
            *reinterpret_cast<ushort4*>(AlB + byteoff) = lv;
        }
        // ---- stage B = Bhi slice: 4 int4/thread ----
        #pragma unroll
        for (int l = 0; l < 4; ++l) {
            int fid = tid + l * 256;       // 0..1023
            int r = fid >> 3;              // n-row 0..127
            int u = fid & 7;               // 16B unit
            int4 bv = *reinterpret_cast<const int4*>(
                &BT[(size_t)(n0 + r) * KC + k0 + u * 8]);
            int byteoff = r * 128 + ((u ^ (r & 7)) << 4);
            *reinterpret_cast<int4*>(BsB + byteoff) = bv;
        }
        __syncthreads();

        // ---- phase 1: Ahi*Bhi + Alo*Bhi ----
        #pragma unroll
        for (int kf = 0; kf < 2; ++kf) {
            bf16x8 afh[4], afl[4], bfr[4];
            #pragma unroll
            for (int fm = 0; fm < 4; ++fm) {
                int row = mw0 + fm * 16 + (lane & 15);
                int unit = kf * 4 + (lane >> 4);
                int off = row * 128 + ((unit ^ (row & 7)) << 4);
                afh[fm] = *reinterpret_cast<bf16x8*>(AhB + off);
                afl[fm] = *reinterpret_cast<bf16x8*>(AlB + off);
            }
            #pragma unroll
            for (int fn = 0; fn < 4; ++fn) {
                int row = nw0 + fn * 16 + (lane & 15);
                int unit = kf * 4 + (lane >> 4);
                bfr[fn] = *reinterpret_cast<bf16x8*>(
                    BsB + row * 128 + ((unit ^ (row & 7)) << 4));
            }
            #pragma unroll
            for (int fm = 0; fm < 4; ++fm)
                #pragma unroll
                for (int fn = 0; fn < 4; ++fn)
                    acc[fm][fn] = __builtin_amdgcn_mfma_f32_16x16x32_bf16(
                        afh[fm], bfr[fn], acc[fm][fn], 0, 0, 0);
            #pragma unroll
            for (int fm = 0; fm < 4; ++fm)
                #pragma unroll
                for (int fn = 0; fn < 4; ++fn)
                    acc[fm][fn] = __builtin_amdgcn_mfma_f32_16x16x32_bf16(
                        afl[fm], bfr[fn], acc[fm][fn], 0, 0, 0);
        }
        __syncthreads();

        // ---- stage B = Blo slice ----
        #pragma unroll
        for (int l = 0; l < 4; ++l) {
            int fid = tid + l * 256;
            int r = fid >> 3;
            int u = fid & 7;
            int4 bv = *reinterpret_cast<const int4*>(
                &BT[(size_t)(n0 + r) * KC + 384 + k0 + u * 8]);
            int byteoff = r * 128 + ((u ^ (r & 7)) << 4);
            *reinterpret_cast<int4*>(BsB + byteoff) = bv;
        }
        __syncthreads();

        // ---- phase 2: Ahi*Blo ----
        #pragma unroll
        for (int kf = 0; kf < 2; ++kf) {
            bf16x8 afh[4], bfr[4];
            #pragma unroll
            for (int fm = 0; fm < 4; ++fm) {
                int row = mw0 + fm * 16 + (lane & 15);
                int unit = kf * 4 + (lane >> 4);
                afh[fm] = *reinterpret_cast<bf16x8*>(
                    AhB + row * 128 + ((unit ^ (row & 7)) << 4));
            }
            #pragma unroll
            for (int fn = 0; fn < 4; ++fn) {
                int row = nw0 + fn * 16 + (lane & 15);
                int unit = kf * 4 + (lane >> 4);
                bfr[fn] = *reinterpret_cast<bf16x8*>(
                    BsB + row * 128 + ((unit ^ (row & 7)) << 4));
            }
            #pragma unroll
            for (int fm = 0; fm < 4; ++fm)
                #pragma unroll
                for (int fn = 0; fn < 4; ++fn)
                    acc[fm][fn] = __builtin_amdgcn_mfma_f32_16x16x32_bf16(
                        afh[fm], bfr[fn], acc[fm][fn], 0, 0, 0);
        }
        __syncthreads();
    }

    // ---- epilogue: C/D layout col=lane&15, row=(lane>>4)*4+reg (m89) ----
    #pragma unroll
    for (int fm = 0; fm < 4; ++fm) {
        #pragma unroll
        for (int fn = 0; fn < 4; ++fn) {
            int col = n0 + nw0 + fn * 16 + (lane & 15);
            float bv = 0.0f;
            if (BIAS) bv = (col < Nbias) ? bias[col] : 0.0f;
            #pragma unroll
            for (int r = 0; r < 4; ++r) {
                int row = m0 + mw0 + fm * 16 + (lane >> 4) * 4 + r;
                C[(size_t)row * Cstride + col] = acc[fm][fn][r] + bv;
            }
        }
    }
}

// ---------------------------------------------------------------------------
// 2x2 mean pool: x[B,56,56,C] -> xp[B,28,28,C], float4-vectorized (G13).
// ---------------------------------------------------------------------------
__global__ void pool_kernel(const float* __restrict__ x, float* __restrict__ xp) {
    int idx = blockIdx.x * blockDim.x + threadIdx.x;
    const int total = BC * PH * PW * (CCH / 4);
    if (idx >= total) return;
    int c4 = idx % (CCH / 4); int t = idx / (CCH / 4);
    int pw = t % PW; t /= PW; int ph = t % PH; int b = t / PH;
    const float* base = x + (((size_t)b * HHH + ph * 2) * WWW + pw * 2) * CCH + c4 * 4;
    const size_t rs = (size_t)WWW * CCH;
    float4 v0 = *reinterpret_cast<const float4*>(base);
    float4 v1 = *reinterpret_cast<const float4*>(base + CCH);
    float4 v2 = *reinterpret_cast<const float4*>(base + rs);
    float4 v3 = *reinterpret_cast<const float4*>(base + rs + CCH);
    float4 o;
    o.x = 0.25f * (v0.x + v1.x + v2.x + v3.x);
    o.y = 0.25f * (v0.y + v1.y + v2.y + v3.y);
    o.z = 0.25f * (v0.z + v1.z + v2.z + v3.z);
    o.w = 0.25f * (v0.w + v1.w + v2.w + v3.w);
    *reinterpret_cast<float4*>(
        xp + (((size_t)(b * PH + ph) * PW + pw) * CCH) + c4 * 4) = o;
}

// ---------------------------------------------------------------------------
// Softmax over k (9 contiguous elems), rows of stride APAD, 108 groups/row.
// ---------------------------------------------------------------------------
__global__ void softmax_kernel(float* __restrict__ a) {
    int idx = blockIdx.x * blockDim.x + threadIdx.x;
    const int total = BC * NP * 108;
    if (idx >= total) return;
    int row = idx / 108;
    int rem = idx % 108;
    float* p = a + (size_t)row * APAD + rem * 9;
    float vbuf[9];
    float m = -1e30f;
    #pragma unroll
    for (int k = 0; k < 9; ++k) { vbuf[k] = p[k] * SCALE; m = fmaxf(m, vbuf[k]); }
    float s = 0.f;
    #pragma unroll
    for (int k = 0; k < 9; ++k) { vbuf[k] = __expf(vbuf[k] - m); s += vbuf[k]; }
    float inv = 1.0f / s;
    #pragma unroll
    for (int k = 0; k < 9; ++k) p[k] = vbuf[k] * inv;
}

// ---------------------------------------------------------------------------
// Gather-fold, float4-vectorized: thread = (pixel, 4-channel group).
// Geometry note: with stride-2 ceil-div from 56, padding is only ever hit on
// the TOP/LEFT (vi0 = 2*ph-1 can be -1; vi0+2 = 2*ph+1 <= 55 always), so
// bottom/right guards are compile-time true and omitted.
// ---------------------------------------------------------------------------
__device__ __forceinline__ void fma4(float4& acc, float w, const float* p) {
    const float4 vv = *reinterpret_cast<const float4*>(p);
    acc.x = fmaf(w, vv.x, acc.x);
    acc.y = fmaf(w, vv.y, acc.y);
    acc.z = fmaf(w, vv.z, acc.z);
    acc.w = fmaf(w, vv.w, acc.w);
}

__global__ __launch_bounds__(256)
void gather_kernel(const float* __restrict__ v, const float* __restrict__ a,
                   float* __restrict__ y) {
    const int idx = blockIdx.x * blockDim.x + threadIdx.x;  // exact grid
    const int c4 = idx % 96;             // float4 channel group
    const int pix = idx / 96;            // b*3136 + i*56 + j
    const int j = pix % WWW;
    const int t = pix / WWW;
    const int i = t % HHH;
    const int b = t / HHH;
    const int n = c4 >> 3;               // head

    int phs[2], qas[2]; int nr = 0;
    if ((i & 1) == 0) { phs[0] = i >> 1; qas[0] = 1; nr = 1; }
    else {
        if (((i + 1) >> 1) < PH) { phs[nr] = (i + 1) >> 1; qas[nr] = 0; ++nr; }
        phs[nr] = (i - 1) >> 1; qas[nr] = 2; ++nr;
    }
    int pws[2], qbs[2]; int nc = 0;
    if ((j & 1) == 0) { pws[0] = j >> 1; qbs[0] = 1; nc = 1; }
    else {
        if (((j + 1) >> 1) < PW) { pws[nc] = (j + 1) >> 1; qbs[nc] = 0; ++nc; }
        pws[nc] = (j - 1) >> 1; qbs[nc] = 2; ++nc;
    }

    const size_t rs = (size_t)WWW * CCH;
    float4 acc = make_float4(0.f, 0.f, 0.f, 0.f);

    for (int ri = 0; ri < nr; ++ri) {
        const int ph = phs[ri];
        const int vi0 = ph * 2 - 1;
        const bool rtop = (vi0 >= 0);
        for (int ci = 0; ci < nc; ++ci) {
            const int pw = pws[ci];
            const int q = qas[ri] * 3 + qbs[ci];
            const float* __restrict__ ap =
                a + (size_t)(b * NP + ph * PW + pw) * APAD + n * 81 + q * 9;
            // preload all 9 weights (always-valid memory)
            const float w0 = ap[0], w1 = ap[1], w2 = ap[2];
            const float w3 = ap[3], w4 = ap[4], w5 = ap[5];
            const float w6 = ap[6], w7 = ap[7], w8 = ap[8];
            const int vj0 = pw * 2 - 1;
            const bool clft = (vj0 >= 0);
            const float* __restrict__ vp =
                v + (((size_t)b * HHH + vi0) * WWW + vj0) * CCH + c4 * 4;
            if (rtop) {
                if (clft) fma4(acc, w0, vp);
                fma4(acc, w1, vp + CCH);
                fma4(acc, w2, vp + 2 * CCH);
            }
            {
                const float* vp1 = vp + rs;
                if (clft) fma4(acc, w3, vp1);
                fma4(acc, w4, vp1 + CCH);
                fma4(acc, w5, vp1 + 2 * CCH);
            }
            {
                const float* vp2 = vp + 2 * rs;
                if (clft) fma4(acc, w6, vp2);
                fma4(acc, w7, vp2 + CCH);
                fma4(acc, w8, vp2 + 2 * CCH);
            }
        }
    }
    *reinterpret_cast<float4*>(y + (size_t)pix * CCH + c4 * 4) = acc;
}

// ---------------------------------------------------------------------------
extern "C" void kernel_launch(void* const* d_in, const int* in_sizes, int n_in,
                              void* d_out, int out_size, void* d_ws, size_t ws_size,
                              hipStream_t stream) {
    const float* x   = (const float*)d_in[0];
    const float* W_v = (const float*)d_in[1];
    const float* W_a = (const float*)d_in[2];
    const float* b_a = (const float*)d_in[3];
    const float* W_o = (const float*)d_in[4];
    const float* b_o = (const float*)d_in[5];
    float* out = (float*)d_out;
    float* ws  = (float*)d_ws;

    // Workspace layout (floats):
    //   Y (ypre, also hosts xp early): 38,535,168   (154.1 MB)
    //   a (stride 1024):               25,690,112   (102.8 MB)
    //   WvT/WaT/WoT bf16:               2,064,384 ushorts (4.1 MB)
    // Total ~261 MB.  v lives in d_out between GEMM1 and GEMM3.
    float*  Y   = ws;
    float*  a   = ws + 38535168;
    ushort* WvT = (ushort*)(ws + 38535168 + 25690112);
    ushort* WaT = WvT + (size_t)384 * KC;
    ushort* WoT = WaT + (size_t)1024 * KC;
    float*  xp  = Y;                 // pool scratch; dead before gather writes Y
    float*  v   = out;               // v lives in d_out until GEMM3 overwrites

    const int M1 = BC * HHH * WWW;   // 100352

    // 0) weight conversions (hi|lo transposed cat layout)
    convw_kernel<<<96,  256, 0, stream>>>(W_v, WvT, 384, 384);
    convw_kernel<<<256, 256, 0, stream>>>(W_a, WaT, NA,  1024);
    convw_kernel<<<96,  256, 0, stream>>>(W_o, WoT, 384, 384);
    // 1) pool into Y-region scratch
    pool_kernel<<<(BC*PH*PW*(CCH/4) + 255) / 256, 256, 0, stream>>>(x, xp);
    // 2) a = xp @ W_a + b_a   (25088 x 1024)
    mfma_gemm<true><<<dim3(8, 196), 256, 0, stream>>>(xp, WaT, b_a, a, APAD, NA);
    // 3) softmax over k
    softmax_kernel<<<(BC*NP*108 + 255) / 256, 256, 0, stream>>>(a);
    // 4) v = x @ W_v -> d_out (100352 x 384)
    mfma_gemm<false><<<dim3(3, 784), 256, 0, stream>>>(x, WvT, nullptr, v, CCH, CCH);
    // 5) gather-fold: reads v (d_out) + a -> writes ypre into Y (ws)
    //    grid: 100352*96 threads / 256 = 37632 blocks (exact)
    gather_kernel<<<37632, 256, 0, stream>>>(v, a, Y);
    // 6) y = ypre @ W_o + b_o: reads Y (ws) -> writes d_out. No alias, no copy.
    mfma_gemm<true><<<dim3(3, 784), 256, 0, stream>>>(Y, WoT, b_o, out, CCH, CCH);
}